// Round 1
// baseline (48.822 us; speedup 1.0000x reference)
//
#include <hip/hip_runtime.h>

// GIoU max-match loss: out = (1/B) * sum_{b,p} (1 - max_g GIoU(pred[b,p], tgt[b,g]))
// B=32, P=2048, G=512 in the bench shapes (derived at runtime from in_sizes).

constexpr float GIOU_EPS = 1e-6f;

__global__ __launch_bounds__(256) void giou_partial_kernel(
    const float4* __restrict__ tgt,    // (B, G) boxes as float4 (x1,y1,x2,y2)
    const float4* __restrict__ pred,   // (B, P) boxes as float4
    float* __restrict__ partial,       // one partial sum per block
    int P, int G)
{
    __shared__ float4 sT[512];
    __shared__ float  sA[512];

    const int b   = blockIdx.y;
    const int tid = threadIdx.x;

    // Stage this batch's target boxes + areas into LDS (coalesced float4 loads).
    for (int g = tid; g < G; g += 256) {
        float4 t = tgt[b * G + g];
        sT[g] = t;
        float tw = fmaxf(t.z - t.x + 1.0f, 0.0f);
        float th = fmaxf(t.w - t.y + 1.0f, 0.0f);
        sA[g] = tw * th;
    }
    __syncthreads();

    const int p = blockIdx.x * 256 + tid;
    float4 pb = pred[b * P + p];
    float pw = fmaxf(pb.z - pb.x + 1.0f, 0.0f);
    float ph = fmaxf(pb.w - pb.y + 1.0f, 0.0f);
    float pa = pw * ph;

    // gious are clipped to [-1,1]; -1.0f is a safe identity for max.
    float m = -1.0f;

    #pragma unroll 4
    for (int g = 0; g < G; ++g) {
        float4 t  = sT[g];       // broadcast read: all lanes same address
        float  ta = sA[g];

        float ix1 = fmaxf(pb.x, t.x);
        float iy1 = fmaxf(pb.y, t.y);
        float ix2 = fminf(pb.z, t.z);
        float iy2 = fminf(pb.w, t.w);
        float iw  = fmaxf(ix2 - ix1 + 1.0f, 0.0f);
        float ih  = fmaxf(iy2 - iy1 + 1.0f, 0.0f);
        float inter = iw * ih;

        float un  = pa + ta - inter;
        float iou = fmaxf(inter * __builtin_amdgcn_rcpf(un), GIOU_EPS);

        float ox1 = fminf(pb.x, t.x);
        float oy1 = fminf(pb.y, t.y);
        float ox2 = fmaxf(pb.z, t.z);
        float oy2 = fmaxf(pb.w, t.w);
        float ow  = fmaxf(ox2 - ox1 + 1.0f, 0.0f);
        float oh  = fmaxf(oy2 - oy1 + 1.0f, 0.0f);
        float outer = ow * oh;

        float gi = iou - (outer - un) * __builtin_amdgcn_rcpf(outer);
        gi = fminf(fmaxf(gi, -1.0f), 1.0f);
        m  = fmaxf(m, gi);
    }

    float v = 1.0f - m;

    // wave (64-lane) reduce, then cross-wave via LDS
    #pragma unroll
    for (int off = 32; off > 0; off >>= 1)
        v += __shfl_down(v, off, 64);

    __shared__ float sW[4];
    const int wid = tid >> 6;
    if ((tid & 63) == 0) sW[wid] = v;
    __syncthreads();
    if (tid == 0)
        partial[blockIdx.y * gridDim.x + blockIdx.x] = sW[0] + sW[1] + sW[2] + sW[3];
}

__global__ __launch_bounds__(256) void giou_reduce_kernel(
    const float* __restrict__ partial, float* __restrict__ out, int n, float invB)
{
    const int tid = threadIdx.x;
    float v = 0.0f;
    for (int i = tid; i < n; i += 256) v += partial[i];

    #pragma unroll
    for (int off = 32; off > 0; off >>= 1)
        v += __shfl_down(v, off, 64);

    __shared__ float sW[4];
    const int wid = tid >> 6;
    if ((tid & 63) == 0) sW[wid] = v;
    __syncthreads();
    if (tid == 0)
        out[0] = (sW[0] + sW[1] + sW[2] + sW[3]) * invB;
}

extern "C" void kernel_launch(void* const* d_in, const int* in_sizes, int n_in,
                              void* d_out, int out_size, void* d_ws, size_t ws_size,
                              hipStream_t stream) {
    const float* imgs_box = (const float*)d_in[0];  // (B, G, 4) fp32
    const float* pre_box  = (const float*)d_in[1];  // (B, P, 4) fp32
    // d_in[2] = labels, only its length (B) matters.

    const int B = in_sizes[2];
    const int G = in_sizes[0] / (4 * B);
    const int P = in_sizes[1] / (4 * B);

    float* partial = (float*)d_ws;

    const int pblocks = (P + 255) / 256;
    dim3 grid(pblocks, B);
    giou_partial_kernel<<<grid, 256, 0, stream>>>(
        (const float4*)imgs_box, (const float4*)pre_box, partial, P, G);

    const int n = pblocks * B;
    giou_reduce_kernel<<<1, 256, 0, stream>>>(partial, (float*)d_out, n, 1.0f / (float)B);
}

// Round 2
// 33.881 us; speedup vs baseline: 1.4410x; 1.4410x over previous
//
#include <hip/hip_runtime.h>

// GIoU max-match loss: out = (1/B) * sum_{b,p} (1 - max_g GIoU(pred[b,p], tgt[b,g]))
// B=32, P=2048, G=512 in the bench shapes (derived at runtime from in_sizes).
//
// Structure: block = 256 threads = 4 waves, covers 64 preds.
//   wave w computes the running max over G-segment [w*G/4, (w+1)*G/4) for all
//   64 preds (lane l owns pred l). Cross-wave max via LDS, then 2-kernel sum.
// Boxes are staged pre-shifted (x2+1, y2+1) so the "+1" width convention is
// folded into the corner min/max. gi is tracked as iou + un/outer (= giou+1),
// which is in (0,2]; the reference's clip to [-1,1] is mathematically a no-op.

constexpr float GIOU_EPS = 1e-6f;

__global__ __launch_bounds__(256) void giou_partial_kernel(
    const float4* __restrict__ tgt,    // (B, G) boxes as float4 (x1,y1,x2,y2)
    const float4* __restrict__ pred,   // (B, P) boxes as float4
    float* __restrict__ partial,       // one partial sum per block
    int P, int G)
{
    __shared__ float4 sT[512];   // pre-shifted target boxes
    __shared__ float  sA[512];   // target areas
    __shared__ float  sM[256];   // cross-wave max exchange

    const int b    = blockIdx.y;
    const int tid  = threadIdx.x;
    const int lane = tid & 63;
    const int wid  = tid >> 6;

    // Stage this batch's target boxes + areas into LDS (coalesced float4 loads).
    for (int g = tid; g < G; g += 256) {
        float4 t = tgt[b * G + g];
        t.z += 1.0f; t.w += 1.0f;                    // pre-shift
        sT[g] = t;
        float tw = fmaxf(t.z - t.x, 0.0f);
        float th = fmaxf(t.w - t.y, 0.0f);
        sA[g] = tw * th;
    }
    __syncthreads();

    const int p = blockIdx.x * 64 + lane;
    float4 pb = pred[b * P + p];
    pb.z += 1.0f; pb.w += 1.0f;                      // pre-shift
    float pw = fmaxf(pb.z - pb.x, 0.0f);
    float ph = fmaxf(pb.w - pb.y, 0.0f);
    float pa = pw * ph;

    // this wave's G-segment
    const int gq = (G + 3) >> 2;
    const int g0 = wid * gq;
    const int g1 = min(g0 + gq, G);

    // m tracks max over g of (giou + 1) in (0, 2]; 0 is a safe identity.
    float m = 0.0f;

    #pragma unroll 4
    for (int g = g0; g < g1; ++g) {
        float4 t  = sT[g];       // broadcast read: all lanes same address
        float  ta = sA[g];

        float ix1 = fmaxf(pb.x, t.x);
        float iy1 = fmaxf(pb.y, t.y);
        float ix2 = fminf(pb.z, t.z);
        float iy2 = fminf(pb.w, t.w);
        float iw  = fmaxf(ix2 - ix1, 0.0f);
        float ih  = fmaxf(iy2 - iy1, 0.0f);
        float inter = iw * ih;

        float un  = pa + ta - inter;
        float iou = fmaxf(inter * __builtin_amdgcn_rcpf(un), GIOU_EPS);

        float ox1 = fminf(pb.x, t.x);
        float oy1 = fminf(pb.y, t.y);
        float ox2 = fmaxf(pb.z, t.z);
        float oy2 = fmaxf(pb.w, t.w);
        float outer = fmaxf(ox2 - ox1, 0.0f) * fmaxf(oy2 - oy1, 0.0f);

        // giou + 1 = iou + un/outer
        float gi = __builtin_fmaf(un, __builtin_amdgcn_rcpf(outer), iou);
        m = fmaxf(m, gi);
    }

    sM[tid] = m;
    __syncthreads();

    if (wid == 0) {
        float mm = fmaxf(fmaxf(sM[lane], sM[lane + 64]),
                         fmaxf(sM[lane + 128], sM[lane + 192]));
        // per-pred loss = 1 - giou = 1 - (mm - 1) = 2 - mm
        float v = 2.0f - mm;
        #pragma unroll
        for (int off = 32; off > 0; off >>= 1)
            v += __shfl_down(v, off, 64);
        if (lane == 0)
            partial[blockIdx.y * gridDim.x + blockIdx.x] = v;
    }
}

__global__ __launch_bounds__(256) void giou_reduce_kernel(
    const float* __restrict__ partial, float* __restrict__ out, int n, float invB)
{
    const int tid = threadIdx.x;
    float v = 0.0f;
    for (int i = tid; i < n; i += 256) v += partial[i];

    #pragma unroll
    for (int off = 32; off > 0; off >>= 1)
        v += __shfl_down(v, off, 64);

    __shared__ float sW[4];
    const int wid = tid >> 6;
    if ((tid & 63) == 0) sW[wid] = v;
    __syncthreads();
    if (tid == 0)
        out[0] = (sW[0] + sW[1] + sW[2] + sW[3]) * invB;
}

extern "C" void kernel_launch(void* const* d_in, const int* in_sizes, int n_in,
                              void* d_out, int out_size, void* d_ws, size_t ws_size,
                              hipStream_t stream) {
    const float* imgs_box = (const float*)d_in[0];  // (B, G, 4) fp32
    const float* pre_box  = (const float*)d_in[1];  // (B, P, 4) fp32
    // d_in[2] = labels, only its length (B) matters.

    const int B = in_sizes[2];
    const int G = in_sizes[0] / (4 * B);
    const int P = in_sizes[1] / (4 * B);

    float* partial = (float*)d_ws;

    const int pblocks = (P + 63) / 64;               // 64 preds per block
    dim3 grid(pblocks, B);
    giou_partial_kernel<<<grid, 256, 0, stream>>>(
        (const float4*)imgs_box, (const float4*)pre_box, partial, P, G);

    const int n = pblocks * B;
    giou_reduce_kernel<<<1, 256, 0, stream>>>(partial, (float*)d_out, n, 1.0f / (float)B);
}